// Round 7
// baseline (995.330 us; speedup 1.0000x reference)
//
#include <hip/hip_runtime.h>
#include <hip/hip_bf16.h>
#include <stdint.h>

typedef __attribute__((ext_vector_type(8))) short s16x8;
typedef __attribute__((ext_vector_type(4))) float f32x4;

__device__ __forceinline__ unsigned short f2bf(float f) {
    unsigned int u = __float_as_uint(f);
    u += 0x7fffu + ((u >> 16) & 1u);   // round-to-nearest-even
    return (unsigned short)(u >> 16);
}

__device__ __forceinline__ void load16_lds(const unsigned short* g, unsigned short* l) {
    __builtin_amdgcn_global_load_lds(
        (const __attribute__((address_space(1))) unsigned int*)g,
        (__attribute__((address_space(3))) unsigned int*)l,
        16, 0, 0);
}

// ---------------- fused fp32 -> bf16 convert over 3 arrays (float4 units) ----------------
__global__ __launch_bounds__(256) void cvt3(
    const float* __restrict__ a, unsigned short* __restrict__ da, int na,
    const float* __restrict__ b, unsigned short* __restrict__ db, int nb,
    const float* __restrict__ c, unsigned short* __restrict__ dc, int nc)
{
    const int total = na + nb + nc;
    for (int i = blockIdx.x * 256 + threadIdx.x; i < total; i += gridDim.x * 256) {
        const float* s; unsigned short* d; int j = i;
        if (j < na)            { s = a; d = da; }
        else if (j < na + nb)  { s = b; d = db; j -= na; }
        else                   { s = c; d = dc; j -= na + nb; }
        float4 v = ((const float4*)s)[j];
        ushort4 o;
        o.x = f2bf(v.x); o.y = f2bf(v.y); o.z = f2bf(v.z); o.w = f2bf(v.w);
        ((ushort4*)d)[j] = o;
    }
}

__global__ __launch_bounds__(256) void recip_k(float* __restrict__ p, int n) {
    int i = blockIdx.x * 256 + threadIdx.x;
    if (i < n) p[i] = 1.0f / p[i];
}

// =====================================================================================
// r7 (= r6 + __launch_bounds__(256,3)): 128x128 tile, 256 threads = 4 waves (2M x 2N).
// 3-slot KH ring (3 x 16KB = 48KB LDS) -> 3 blocks/CU co-resident: independent blocks
// overlap each other's barrier drains, prologues and epilogues (m114 mechanism).
// Counted vmcnt: prologue stages KH0,1; phase j waits vmcnt(4) (retires exactly KH j,
// leaves KH j+1 in flight), barrier, stages KH j+2 into slot (j-1)%3, computes slot j%3.
// Tail: j+1==NKH -> vmcnt(0). Slot (j-1)%3 overwrite is safe: its readers (phase j-1
// ds_reads) are consumed by phase j-1 MFMAs before that wave reaches the phase-j barrier.
// MODE 0: bf16 out + bias. MODE 1: bf16+bias transposed store (v-proj).
// MODE 2: bf16 exp(acc*scale) + rowsum atomics. MODE 3: f32 out * rowinv[row].
// =====================================================================================
template <int MODE>
__global__ __launch_bounds__(256, 3) void gemm_bt(
    const unsigned short* __restrict__ A, const unsigned short* __restrict__ B,
    void* __restrict__ Cv, const float* __restrict__ bias,
    float* __restrict__ rowsum, const float* __restrict__ rowinv, float scale,
    int M, int N, int K,
    long long strideA, long long strideB, long long strideC)
{
    __shared__ unsigned short sh[24576];   // 48 KiB: 3 ring slots x (A[128][32] + B[128][32])

    const int batch = blockIdx.y;
    A += (long long)batch * strideA;
    B += (long long)batch * strideB;

    // tile coords; XCD-aware bijective rectangles for the batched attention GEMMs.
    int tm, tn;
    if (MODE == 2) {                       // 16x16 tiles/batch (256 blk): 4tm x 8tn per XCD
        const int xcd = blockIdx.x & 7, idx = blockIdx.x >> 3;   // idx 0..31
        tm = 4 * (xcd >> 1) + (idx >> 3);
        tn = 8 * (xcd & 1) + (idx & 7);
    } else if (MODE == 3) {                // 16x8 tiles/batch (128 blk): 4tm x 4tn per XCD
        const int xcd = blockIdx.x & 7, idx = blockIdx.x >> 3;   // idx 0..15
        tm = 4 * (xcd >> 1) + (idx >> 2);
        tn = 4 * (xcd & 1) + (idx & 3);
    } else {                               // projections: ntn=8 -> xcd==tn slice of W: ideal
        const int ntn = N >> 7;
        tm = blockIdx.x / ntn;
        tn = blockIdx.x % ntn;
    }

    const int tid  = threadIdx.x;
    const int wave = tid >> 6;
    const int lane = tid & 63;
    const int quad = lane >> 4;
    const int l16  = lane & 15;
    const int wm   = (wave >> 1) * 64;
    const int wn   = (wave & 1) * 64;

    // staging: per KH, 4 units [A rows0-63, A rows64-127, B rows0-63, B rows64-127],
    // each [64][32] row-major; wave covers 16 rows x 4 k-chunks; LDS dst = base+lane*16B.
    const int srow = (wave << 4) + (lane >> 2);          // 0..63
    const int scol = (lane & 3) << 3;                    // 0,8,16,24
    const unsigned short* gA0 = A + (long long)(tm * 128 +      srow) * K + scol;
    const unsigned short* gA1 = A + (long long)(tm * 128 + 64 + srow) * K + scol;
    const unsigned short* gB0 = B + (long long)(tn * 128 +      srow) * K + scol;
    const unsigned short* gB1 = B + (long long)(tn * 128 + 64 + srow) * K + scol;
    const int sdst = wave * 512;                         // wave-uniform short offset in unit

    const int NKH = K >> 5;                              // 32-wide K-halves (>= 24 here)

    f32x4 acc[4][4] = {};

    // prologue: stage KH0 -> slot0, KH1 -> slot1 (8 loads/thread in KH order)
    {
        load16_lds(gA0, sh +        sdst);
        load16_lds(gA1, sh + 2048 + sdst);
        load16_lds(gB0, sh + 4096 + sdst);
        load16_lds(gB1, sh + 6144 + sdst);
        load16_lds(gA0 + 32, sh + 8192 +        sdst);
        load16_lds(gA1 + 32, sh + 8192 + 2048 + sdst);
        load16_lds(gB0 + 32, sh + 8192 + 4096 + sdst);
        load16_lds(gB1 + 32, sh + 8192 + 6144 + sdst);
    }

    int cs = 0;                                          // slot holding KH j
    for (int j = 0; j < NKH; ++j) {
        // ---- retire KH j (own loads), then block-wide join ----
        __builtin_amdgcn_sched_barrier(0);
        if (j + 1 < NKH) { asm volatile("s_waitcnt vmcnt(4)" ::: "memory"); }
        else             { asm volatile("s_waitcnt vmcnt(0)" ::: "memory"); }
        __builtin_amdgcn_s_barrier();
        __builtin_amdgcn_sched_barrier(0);

        // ---- stage KH j+2 into slot (j+2)%3 == (j-1)%3 (freed by the barrier) ----
        if (j + 2 < NKH) {
            unsigned short* sb = sh + (cs ? cs - 1 : 2) * 8192;
            const int kof = (j + 2) * 32;
            load16_lds(gA0 + kof, sb +        sdst);
            load16_lds(gA1 + kof, sb + 2048 + sdst);
            load16_lds(gB0 + kof, sb + 4096 + sdst);
            load16_lds(gB1 + kof, sb + 6144 + sdst);
        }
        __builtin_amdgcn_sched_barrier(0);   // stage issued early; interior free below

        // ---- compute slot cs: 8 ds_read_b128 + 16 MFMA, compiler-scheduled ----
        const unsigned short* lA = sh + cs * 8192;
        const unsigned short* lB = lA + 4096;

        __builtin_amdgcn_s_setprio(1);
        s16x8 af[4], bfr[4];
#pragma unroll
        for (int i = 0; i < 4; ++i)
            af[i] = *(const s16x8*)&lA[(wm + i * 16 + l16) * 32 + quad * 8];
#pragma unroll
        for (int n = 0; n < 4; ++n)
            bfr[n] = *(const s16x8*)&lB[(wn + n * 16 + l16) * 32 + quad * 8];
#pragma unroll
        for (int i = 0; i < 4; ++i)
#pragma unroll
            for (int n = 0; n < 4; ++n)
                acc[i][n] = __builtin_amdgcn_mfma_f32_16x16x32_bf16(af[i], bfr[n], acc[i][n], 0, 0, 0);
        __builtin_amdgcn_s_setprio(0);

        cs = (cs == 2) ? 0 : cs + 1;
    }
    // last phase waited vmcnt(0); all ds_reads consumed by MFMAs: clean epilogue entry.

    // C/D layout: col = lane&15, row = quad*4 + reg
    if (MODE == 0) {
        unsigned short* C = (unsigned short*)Cv + (long long)batch * strideC;
#pragma unroll
        for (int i = 0; i < 4; ++i) {
            const int m0 = tm * 128 + wm + i * 16 + quad * 4;
#pragma unroll
            for (int n = 0; n < 4; ++n) {
                const int c = tn * 128 + wn + n * 16 + l16;
                const float bv = bias[c];
#pragma unroll
                for (int r = 0; r < 4; ++r)
                    C[(long long)(m0 + r) * N + c] = f2bf(acc[i][n][r] + bv);
            }
        }
    } else if (MODE == 2) {
        unsigned short* C = (unsigned short*)Cv + (long long)batch * strideC;
        float psum[4][4];
#pragma unroll
        for (int i = 0; i < 4; ++i)
#pragma unroll
            for (int r = 0; r < 4; ++r) psum[i][r] = 0.0f;
#pragma unroll
        for (int i = 0; i < 4; ++i) {
            const int m0 = tm * 128 + wm + i * 16 + quad * 4;
#pragma unroll
            for (int n = 0; n < 4; ++n) {
                const int c = tn * 128 + wn + n * 16 + l16;
#pragma unroll
                for (int r = 0; r < 4; ++r) {
                    float e = __expf(acc[i][n][r] * scale);
                    C[(long long)(m0 + r) * N + c] = f2bf(e);
                    psum[i][r] += e;
                }
            }
        }
        float* rs = rowsum + (long long)batch * 2048;
#pragma unroll
        for (int i = 0; i < 4; ++i) {
            const int m0 = tm * 128 + wm + i * 16 + quad * 4;
#pragma unroll
            for (int r = 0; r < 4; ++r) {
                float v = psum[i][r];
                v += __shfl_xor(v, 1);
                v += __shfl_xor(v, 2);
                v += __shfl_xor(v, 4);
                v += __shfl_xor(v, 8);
                if (l16 == 0) atomicAdd(&rs[m0 + r], v);
            }
        }
    } else if (MODE == 3) {
        float* C = (float*)Cv + (long long)batch * strideC;
        const float* ri = rowinv + (long long)batch * 2048;
#pragma unroll
        for (int i = 0; i < 4; ++i) {
            const int m0 = tm * 128 + wm + i * 16 + quad * 4;
            const float4 inv4 = *(const float4*)&ri[m0];
#pragma unroll
            for (int n = 0; n < 4; ++n) {
                const int c = tn * 128 + wn + n * 16 + l16;
                C[(long long)(m0 + 0) * N + c] = acc[i][n][0] * inv4.x;
                C[(long long)(m0 + 1) * N + c] = acc[i][n][1] * inv4.y;
                C[(long long)(m0 + 2) * N + c] = acc[i][n][2] * inv4.z;
                C[(long long)(m0 + 3) * N + c] = acc[i][n][3] * inv4.w;
            }
        }
    } else { // MODE 1: transposed bf16 store through LDS (v-proj only).
        // Output vT[batch][o][s]: row len 2048, batch stride 1024*2048.
        const int batch_o = (tm * 128) >> 11;
        const int s0 = (tm * 128) & 2047;
        unsigned short* out = (unsigned short*)Cv + (long long)batch_o * 2097152LL + s0;
        const int STR = 132;  // padded row stride (shorts)
#pragma unroll
        for (int c = 0; c < 4; ++c) {           // chunk: 32 o-rows
            __syncthreads();                    // sh free (K-loop or prev chunk done)
            if ((wn >> 6) == (c >> 1)) {
                const int jbase = (c & 1) * 2;
#pragma unroll
                for (int jj = 0; jj < 2; ++jj) {
                    const int j = jbase + jj;
                    const int nnl = j * 16 + l16 - (c & 1) * 32;        // 0..31
                    const float bv = bias[tn * 128 + wn + j * 16 + l16];
#pragma unroll
                    for (int i = 0; i < 4; ++i) {
                        const int mmb = wm + i * 16 + quad * 4;
#pragma unroll
                        for (int r = 0; r < 4; ++r)
                            sh[nnl * STR + mmb + r] = f2bf(acc[i][j][r] + bv);
                    }
                }
            }
            __syncthreads();
            // copy 32 rows x 128 shorts (8 B per thread per pass, coalesced 256 B rows)
#pragma unroll
            for (int rr = 0; rr < 4; ++rr) {
                const int row = rr * 8 + (tid >> 5);     // 0..31
                const int csh = (tid & 31) * 4;          // short offset in row
                unsigned long long v8 = *(const unsigned long long*)&sh[row * STR + csh];
                *(unsigned long long*)&out[(long long)(tn * 128 + c * 32 + row) * 2048 + csh] = v8;
            }
        }
    }
}

extern "C" void kernel_launch(void* const* d_in, const int* in_sizes, int n_in,
                              void* d_out, int out_size, void* d_ws, size_t ws_size,
                              hipStream_t stream) {
    const float* query = (const float*)d_in[0];   // [16,2048,1024]
    const float* key   = (const float*)d_in[1];   // [16,2048,768]
    const float* value = (const float*)d_in[2];   // [16,2048,768]
    const float* Wq    = (const float*)d_in[3];   // [1024,1024]
    const float* bq    = (const float*)d_in[4];
    const float* Wk    = (const float*)d_in[5];   // [1024,768]
    const float* bk    = (const float*)d_in[6];
    const float* Wv    = (const float*)d_in[7];   // [1024,768]
    const float* bv    = (const float*)d_in[8];

    char* ws = (char*)d_ws;
    unsigned short* qin = (unsigned short*)ws;                    // 33,554,432 elems
    unsigned short* kin = qin + 33554432LL;                       // 25,165,824
    unsigned short* vin = kin + 25165824LL;                       // 25,165,824
    unsigned short* Sb  = (unsigned short*)ws;                    // alias (after projections)
    float* rowsum = (float*)(ws + 134217728LL);                   // 32768 f32
    unsigned short* Wqb = (unsigned short*)(ws + 167772160LL);    // 1,048,576
    unsigned short* Wkb = Wqb + 1048576LL;                        // 786,432
    unsigned short* Wvb = Wkb + 786432LL;                         // 786,432
    unsigned short* qp  = (unsigned short*)(ws + 173015040LL);    // 33,554,432
    unsigned short* kp  = qp + 33554432LL;                        // 33,554,432
    unsigned short* vT  = kp + 33554432LL;                        // 33,554,432 ([16][1024][2048])

    dim3 blk(256);

    // 1) converts
    cvt3<<<8192, blk, 0, stream>>>(query, qin, 33554432 / 4,
                                   key,   kin, 25165824 / 4,
                                   value, vin, 25165824 / 4);
    cvt3<<<2560, blk, 0, stream>>>(Wq, Wqb, 1048576 / 4,
                                   Wk, Wkb, 786432 / 4,
                                   Wv, Wvb, 786432 / 4);

    // 2) projections (all on the 128^2 ring kernel; v keeps fused transpose epilogue)
    gemm_bt<0><<<dim3(2048, 1), blk, 0, stream>>>(qin, Wqb, qp, bq, nullptr, nullptr, 0.f,
                                                  32768, 1024, 1024, 0, 0, 0);
    gemm_bt<0><<<dim3(2048, 1), blk, 0, stream>>>(kin, Wkb, kp, bk, nullptr, nullptr, 0.f,
                                                  32768, 1024, 768, 0, 0, 0);
    gemm_bt<1><<<dim3(2048, 1), blk, 0, stream>>>(vin, Wvb, vT, bv, nullptr, nullptr, 0.f,
                                                  32768, 1024, 768, 0, 0, 0);

    // 3) zero row sums
    hipMemsetAsync(rowsum, 0, 32768 * sizeof(float), stream);

    // 4) S~ = exp(q.k^T * scale), bf16, + row sums  (batched x16)
    gemm_bt<2><<<dim3(256, 16), blk, 0, stream>>>(qp, kp, Sb, nullptr, rowsum, nullptr, 0.03125f,
                                                  2048, 2048, 1024, 2097152LL, 2097152LL, 4194304LL);

    // 5) rowsum -> 1/rowsum
    recip_k<<<128, blk, 0, stream>>>(rowsum, 32768);

    // 6) O = (S~ . vT) * rowinv  (batched x16), fp32 out
    gemm_bt<3><<<dim3(128, 16), blk, 0, stream>>>(Sb, vT, (float*)d_out, nullptr, nullptr, rowsum, 1.0f,
                                                  2048, 1024, 2048, 4194304LL, 2097152LL, 2097152LL);
}